// Round 2
// baseline (582.425 us; speedup 1.0000x reference)
//
#include <hip/hip_runtime.h>

#define N_NODES 10000
#define E_EDGES 320000
#define NH 4
#define HOPS 3

// ---------------- CSR build ----------------
__global__ void k_count(const int* __restrict__ dst, int* __restrict__ counts){
  int e = blockIdx.x*256 + threadIdx.x;
  if(e < E_EDGES) atomicAdd(&counts[dst[e]], 1);
}

__global__ void k_scan(const int* __restrict__ counts, int* __restrict__ row_ptr, int* __restrict__ fillp){
  __shared__ int sm[256];
  __shared__ int carry;
  int t = threadIdx.x;
  if(t==0){ carry = 0; row_ptr[0] = 0; }
  __syncthreads();
  for(int base=0; base<N_NODES; base+=256){
    int v = (base+t < N_NODES) ? counts[base+t] : 0;
    sm[t] = v; __syncthreads();
    for(int off=1; off<256; off<<=1){
      int add = (t>=off) ? sm[t-off] : 0;
      __syncthreads();
      sm[t] += add;
      __syncthreads();
    }
    if(base+t < N_NODES){
      row_ptr[base+t+1] = carry + sm[t];
      fillp[base+t]     = carry + sm[t] - v;   // exclusive
    }
    __syncthreads();
    if(t==0) carry += sm[255];
    __syncthreads();
  }
}

__global__ void k_fill(const int* __restrict__ src, const int* __restrict__ dst,
                       int* __restrict__ fillp, int* __restrict__ csr_eid, int* __restrict__ sorted_src){
  int e = blockIdx.x*256 + threadIdx.x;
  if(e < E_EDGES){
    int d = dst[e];
    int pos = atomicAdd(&fillp[d], 1);
    csr_eid[pos] = e;
    sorted_src[pos] = src[e];
  }
}

// ---------------- b_edge[hop][c][h] = sum_f Wes[hop][c][h*128+f] * a_edge[hop][h][f]
__global__ void k_bedge(const float* __restrict__ Wes, const float* __restrict__ a_edge,
                        float* __restrict__ b_edge){
  int idx = blockIdx.x*256 + threadIdx.x;
  if(idx >= HOPS*64*NH) return;
  int hop = idx/(64*NH); int c = (idx/NH)%64; int h = idx%NH;
  const float* we = Wes + (size_t)hop*64*512 + (size_t)c*512 + h*128;
  const float* ae = a_edge + (size_t)hop*NH*128 + h*128;
  float s = 0.f;
  for(int f=0; f<128; f++) s += we[f] * ae[f];
  b_edge[idx] = s;
}

// ---------------- alpha_e for all hops, in CSR-sorted order ----------------
__global__ __launch_bounds__(256) void k_alpha_e(const float* __restrict__ edge_fts,
                        const int* __restrict__ csr_eid, const float* __restrict__ b_edge,
                        float* __restrict__ ae_sorted){
  __shared__ float bl[HOPS*64*NH];
  for(int i=threadIdx.x; i<HOPS*64*NH; i+=256) bl[i] = b_edge[i];
  __syncthreads();
  int pos = blockIdx.x*256 + threadIdx.x;
  if(pos >= E_EDGES) return;
  int e = csr_eid[pos];
  const float* ef = edge_fts + (size_t)e*64;
  float acc[HOPS*NH];
  #pragma unroll
  for(int i=0;i<HOPS*NH;i++) acc[i]=0.f;
  for(int c=0; c<64; c+=4){
    float4 xv = *(const float4*)(ef + c);
    float x[4] = {xv.x, xv.y, xv.z, xv.w};
    #pragma unroll
    for(int j=0;j<4;j++){
      float xc = x[j]; int cc = c+j;
      #pragma unroll
      for(int hh=0; hh<HOPS*NH; hh++){
        int hop = hh>>2, h = hh&3;
        acc[hh] += xc * bl[hop*256 + cc*4 + h];
      }
    }
  }
  #pragma unroll
  for(int hop=0; hop<HOPS; hop++){
    *(float4*)(ae_sorted + ((size_t)hop*E_EDGES + pos)*4) =
      make_float4(acc[hop*4+0], acc[hop*4+1], acc[hop*4+2], acc[hop*4+3]);
  }
}

// ---------------- proj GEMM: h_all[N,512] = x[N,128] @ W[128,512] ----------------
__global__ __launch_bounds__(256) void k_proj(const float* __restrict__ x, const float* __restrict__ W,
                       float* __restrict__ h_all){
  __shared__ float Asm[64][132];
  __shared__ float Bsm[128][64];
  int t = threadIdx.x;
  int row0 = blockIdx.x*64;
  int col0 = blockIdx.y*64;
  {
    int r = t>>5;           // 0..7
    int k4 = (t&31)<<2;     // 0..124
    #pragma unroll
    for(int rr=0; rr<64; rr+=8){
      int row = row0 + rr + r;
      float4 v = make_float4(0.f,0.f,0.f,0.f);
      if(row < N_NODES) v = *(const float4*)(x + (size_t)row*128 + k4);
      *(float4*)&Asm[rr+r][k4] = v;
    }
  }
  {
    int kr = t>>4;          // 0..15
    int c4 = (t&15)<<2;     // 0..60
    #pragma unroll
    for(int kk=0; kk<128; kk+=16){
      float4 u = *(const float4*)(W + (size_t)(kk+kr)*512 + col0 + c4);
      *(float4*)&Bsm[kk+kr][c4] = u;
    }
  }
  __syncthreads();
  int tr = t>>4, tc = t&15;
  int r0 = tr<<2, c0 = tc<<2;
  float acc[4][4] = {};
  #pragma unroll 4
  for(int k=0; k<128; k++){
    float a[4];
    #pragma unroll
    for(int i=0;i<4;i++) a[i] = Asm[r0+i][k];
    float4 bv = *(const float4*)&Bsm[k][c0];
    float b[4] = {bv.x, bv.y, bv.z, bv.w};
    #pragma unroll
    for(int i=0;i<4;i++)
      #pragma unroll
      for(int j=0;j<4;j++) acc[i][j] += a[i]*b[j];
  }
  #pragma unroll
  for(int i=0;i<4;i++){
    int row = row0 + r0 + i;
    if(row < N_NODES)
      *(float4*)(h_all + (size_t)row*512 + col0 + c0) =
        make_float4(acc[i][0],acc[i][1],acc[i][2],acc[i][3]);
  }
}

// ---------------- s_src[n,h], s_dst[n,h] ----------------
__global__ __launch_bounds__(256) void k_s(const float* __restrict__ h_all, const float* __restrict__ asrc,
                    const float* __restrict__ adst, float* __restrict__ s_src, float* __restrict__ s_dst){
  int n = blockIdx.x; int t = threadIdx.x;
  int h = t>>6; int f0 = (t&63)<<1;
  float2 hv = *(const float2*)(h_all + (size_t)n*512 + (h<<7) + f0);
  int ai = (h<<7) + f0;
  float ps = hv.x*asrc[ai] + hv.y*asrc[ai+1];
  float pd = hv.x*adst[ai] + hv.y*adst[ai+1];
  #pragma unroll
  for(int off=32; off; off>>=1){ ps += __shfl_xor(ps,off); pd += __shfl_xor(pd,off); }
  if((t&63)==0){ s_src[n*4+h] = ps; s_dst[n*4+h] = pd; }
}

// ---------------- per-node softmax over incoming edges ----------------
__global__ __launch_bounds__(64) void k_softmax(const float* __restrict__ ae, const float* __restrict__ s_src,
                          const float* __restrict__ s_dst, const int* __restrict__ sorted_src,
                          const int* __restrict__ row_ptr, float* __restrict__ ew, float* __restrict__ denom){
  int n = blockIdx.x; int lane = threadIdx.x;
  int start = row_ptr[n], end = row_ptr[n+1];
  float4 sd = *(const float4*)(s_dst + n*4);
  float m0=-1e30f, m1=-1e30f, m2=-1e30f, m3=-1e30f;
  for(int pos=start+lane; pos<end; pos+=64){
    int s = sorted_src[pos];
    float4 ss = *(const float4*)(s_src + s*4);
    float4 av = *(const float4*)(ae + (size_t)pos*4);
    float a0 = ss.x+sd.x+av.x; a0 = (a0>0.f)? a0 : 0.2f*a0;
    float a1 = ss.y+sd.y+av.y; a1 = (a1>0.f)? a1 : 0.2f*a1;
    float a2 = ss.z+sd.z+av.z; a2 = (a2>0.f)? a2 : 0.2f*a2;
    float a3 = ss.w+sd.w+av.w; a3 = (a3>0.f)? a3 : 0.2f*a3;
    *(float4*)(ew + (size_t)pos*4) = make_float4(a0,a1,a2,a3);
    m0=fmaxf(m0,a0); m1=fmaxf(m1,a1); m2=fmaxf(m2,a2); m3=fmaxf(m3,a3);
  }
  #pragma unroll
  for(int off=32; off; off>>=1){
    m0=fmaxf(m0,__shfl_xor(m0,off)); m1=fmaxf(m1,__shfl_xor(m1,off));
    m2=fmaxf(m2,__shfl_xor(m2,off)); m3=fmaxf(m3,__shfl_xor(m3,off));
  }
  float s0=0,s1=0,s2=0,s3=0;
  for(int pos=start+lane; pos<end; pos+=64){
    float4 a = *(const float4*)(ew + (size_t)pos*4);
    float w0=__expf(a.x-m0), w1=__expf(a.y-m1), w2=__expf(a.z-m2), w3=__expf(a.w-m3);
    *(float4*)(ew + (size_t)pos*4) = make_float4(w0,w1,w2,w3);
    s0+=w0; s1+=w1; s2+=w2; s3+=w3;
  }
  #pragma unroll
  for(int off=32; off; off>>=1){
    s0+=__shfl_xor(s0,off); s1+=__shfl_xor(s1,off);
    s2+=__shfl_xor(s2,off); s3+=__shfl_xor(s3,off);
  }
  if(lane==0) *(float4*)(denom + n*4) = make_float4(s0+1e-16f, s1+1e-16f, s2+1e-16f, s3+1e-16f);
}

// ---------------- aggregate: out[n,f] = mean_h sum_e w*h_src / denom ----------------
__global__ __launch_bounds__(256) void k_agg(const float* __restrict__ h_all, const float* __restrict__ ew,
                      const float* __restrict__ denom, const int* __restrict__ sorted_src,
                      const int* __restrict__ row_ptr, float* __restrict__ xout){
  __shared__ float red[512];
  int n = blockIdx.x; int t = threadIdx.x;
  int h = t>>6; int f0 = (t&63)<<1;
  int start = row_ptr[n], end = row_ptr[n+1];
  float ax=0.f, ay=0.f;
  int pos = start;
  for(; pos+1 < end; pos+=2){
    int s0 = sorted_src[pos], s1 = sorted_src[pos+1];
    float w0 = ew[(size_t)pos*4 + h], w1 = ew[(size_t)(pos+1)*4 + h];
    float2 v0 = *(const float2*)(h_all + (size_t)s0*512 + (h<<7) + f0);
    float2 v1 = *(const float2*)(h_all + (size_t)s1*512 + (h<<7) + f0);
    ax += w0*v0.x + w1*v1.x;
    ay += w0*v0.y + w1*v1.y;
  }
  if(pos < end){
    int s0 = sorted_src[pos];
    float w0 = ew[(size_t)pos*4 + h];
    float2 v0 = *(const float2*)(h_all + (size_t)s0*512 + (h<<7) + f0);
    ax += w0*v0.x; ay += w0*v0.y;
  }
  float inv = 1.0f / denom[n*4+h];
  red[(h<<7)+f0]   = ax*inv;
  red[(h<<7)+f0+1] = ay*inv;
  __syncthreads();
  if(t < 64){
    int f = t<<1;
    float v0 = 0.25f*(red[f]   + red[128+f]   + red[256+f]   + red[384+f]);
    float v1 = 0.25f*(red[f+1] + red[128+f+1] + red[256+f+1] + red[384+f+1]);
    *(float2*)(xout + (size_t)n*128 + f) = make_float2(v0,v1);
  }
}

// ---------------- gated residual: x = g*curr + (1-g)*prior, g = sigmoid(prior@Wp + curr@Wc)
__global__ __launch_bounds__(128) void k_gate(const float* __restrict__ prior, const float* __restrict__ curr,
                       const float* __restrict__ Wp, const float* __restrict__ Wc,
                       float* __restrict__ xnew){
  __shared__ float pr[128], cu[128];
  int n = blockIdx.x; int t = threadIdx.x;
  pr[t] = prior[(size_t)n*128 + t];
  cu[t] = curr[(size_t)n*128 + t];
  __syncthreads();
  float accp=0.f, accc=0.f;
  #pragma unroll 4
  for(int k=0; k<128; k++){
    accp += pr[k] * Wp[(size_t)k*128 + t];
    accc += cu[k] * Wc[(size_t)k*128 + t];
  }
  float z = accp + accc;
  float g = 1.f/(1.f + __expf(-z));
  xnew[(size_t)n*128 + t] = g*cu[t] + (1.f-g)*pr[t];
}

extern "C" void kernel_launch(void* const* d_in, const int* in_sizes, int n_in,
                              void* d_out, int out_size, void* d_ws, size_t ws_size,
                              hipStream_t stream){
  (void)in_sizes; (void)n_in; (void)out_size; (void)ws_size;
  const float* node_fts = (const float*)d_in[0];
  const float* edge_fts = (const float*)d_in[1];
  const int*   edges    = (const int*)d_in[2];
  const float* Ws       = (const float*)d_in[3];
  const float* Wes      = (const float*)d_in[4];
  const float* a_src    = (const float*)d_in[5];
  const float* a_dst    = (const float*)d_in[6];
  const float* a_edge   = (const float*)d_in[7];
  const float* W_prior  = (const float*)d_in[8];
  const float* W_curr   = (const float*)d_in[9];

  char* ws = (char*)d_ws;
  size_t off = 0;
  auto alloc = [&](size_t bytes)->void*{
    void* p = ws + off;
    off += (bytes + 255) & ~(size_t)255;
    return p;
  };
  int*   counts     = (int*)  alloc((size_t)N_NODES*4);
  int*   row_ptr    = (int*)  alloc((size_t)(N_NODES+1)*4);
  int*   fillp      = (int*)  alloc((size_t)N_NODES*4);
  int*   csr_eid    = (int*)  alloc((size_t)E_EDGES*4);
  int*   sorted_src = (int*)  alloc((size_t)E_EDGES*4);
  float* b_edge     = (float*)alloc((size_t)HOPS*64*NH*4);
  float* ae_sorted  = (float*)alloc((size_t)HOPS*E_EDGES*NH*4);
  float* h_all      = (float*)alloc((size_t)N_NODES*512*4);
  float* s_src      = (float*)alloc((size_t)N_NODES*NH*4);
  float* s_dst      = (float*)alloc((size_t)N_NODES*NH*4);
  float* ew         = (float*)alloc((size_t)E_EDGES*NH*4);
  float* denom      = (float*)alloc((size_t)N_NODES*NH*4);
  float* xbuf       = (float*)alloc((size_t)N_NODES*128*4);
  float* curbuf     = (float*)alloc((size_t)N_NODES*128*4);

  const int* src = edges;
  const int* dst = edges + E_EDGES;

  hipMemsetAsync(counts, 0, (size_t)N_NODES*4, stream);
  k_count<<<(E_EDGES+255)/256, 256, 0, stream>>>(dst, counts);
  k_scan<<<1, 256, 0, stream>>>(counts, row_ptr, fillp);
  k_fill<<<(E_EDGES+255)/256, 256, 0, stream>>>(src, dst, fillp, csr_eid, sorted_src);
  k_bedge<<<3, 256, 0, stream>>>(Wes, a_edge, b_edge);
  k_alpha_e<<<(E_EDGES+255)/256, 256, 0, stream>>>(edge_fts, csr_eid, b_edge, ae_sorted);

  for(int hop=0; hop<HOPS; hop++){
    const float* xin = (hop==0) ? node_fts : xbuf;
    k_proj<<<dim3((N_NODES+63)/64, 8), 256, 0, stream>>>(xin, Ws + (size_t)hop*128*512, h_all);
    k_s<<<N_NODES, 256, 0, stream>>>(h_all, a_src + (size_t)hop*512, a_dst + (size_t)hop*512, s_src, s_dst);
    k_softmax<<<N_NODES, 64, 0, stream>>>(ae_sorted + (size_t)hop*E_EDGES*4, s_src, s_dst,
                                          sorted_src, row_ptr, ew, denom);
    float* xout = (hop==0) ? xbuf : curbuf;
    k_agg<<<N_NODES, 256, 0, stream>>>(h_all, ew, denom, sorted_src, row_ptr, xout);
    if(hop > 0){
      float* xnew = (hop == HOPS-1) ? (float*)d_out : xbuf;
      k_gate<<<N_NODES, 128, 0, stream>>>(xbuf, curbuf, W_prior, W_curr, xnew);
    }
  }
}

// Round 4
// 421.937 us; speedup vs baseline: 1.3804x; 1.3804x over previous
//
#include <hip/hip_runtime.h>
#include <hip/hip_fp16.h>

#define N_NODES 10000
#define E_EDGES 320000
#define NH 4
#define HOPS 3
#define MAXD 512

// ---------------- CSR build ----------------
__global__ void k_count(const int* __restrict__ dst, int* __restrict__ counts){
  int e = blockIdx.x*256 + threadIdx.x;
  if(e < E_EDGES) atomicAdd(&counts[dst[e]], 1);
}

// one block, 1024 threads, 10 elements/thread
__global__ __launch_bounds__(1024) void k_scan(const int* __restrict__ counts,
                                               int* __restrict__ row_ptr, int* __restrict__ fillp){
  __shared__ int sm[1024];
  int t = threadIdx.x;
  const int CH = 10;                   // 1024*10 = 10240 >= N_NODES
  int base = t*CH;
  int loc[CH]; int sum = 0;
  #pragma unroll
  for(int i=0;i<CH;i++){
    int v = (base+i < N_NODES) ? counts[base+i] : 0;
    loc[i] = sum; sum += v;
  }
  sm[t] = sum; __syncthreads();
  for(int off=1; off<1024; off<<=1){
    int add = (t>=off) ? sm[t-off] : 0;
    __syncthreads();
    sm[t] += add;
    __syncthreads();
  }
  int excl = (t>0) ? sm[t-1] : 0;
  #pragma unroll
  for(int i=0;i<CH;i++){
    int n = base+i;
    if(n < N_NODES){
      int e = excl + loc[i];
      row_ptr[n] = e;
      fillp[n]   = e;
    }
  }
  if(t==1023) row_ptr[N_NODES] = sm[1023];
}

__global__ void k_fill(const int* __restrict__ src, const int* __restrict__ dst,
                       int* __restrict__ fillp, int* __restrict__ csr_eid, int* __restrict__ sorted_src){
  int e = blockIdx.x*256 + threadIdx.x;
  if(e < E_EDGES){
    int d = dst[e];
    int pos = atomicAdd(&fillp[d], 1);
    csr_eid[pos] = e;
    sorted_src[pos] = src[e];
  }
}

// ---------------- b_edge[hop][c][h] = sum_f Wes[hop][c][h*128+f] * a_edge[hop][h][f]
__global__ void k_bedge(const float* __restrict__ Wes, const float* __restrict__ a_edge,
                        float* __restrict__ b_edge){
  int idx = blockIdx.x*256 + threadIdx.x;
  if(idx >= HOPS*64*NH) return;
  int hop = idx/(64*NH); int c = (idx/NH)%64; int h = idx%NH;
  const float* we = Wes + (size_t)hop*64*512 + (size_t)c*512 + h*128;
  const float* ae = a_edge + (size_t)hop*NH*128 + h*128;
  float s = 0.f;
  for(int f=0; f<128; f++) s += we[f] * ae[f];
  b_edge[idx] = s;
}

// ---------------- alpha_e for all hops, in CSR-sorted order ----------------
__global__ __launch_bounds__(256) void k_alpha_e(const float* __restrict__ edge_fts,
                        const int* __restrict__ csr_eid, const float* __restrict__ b_edge,
                        float* __restrict__ ae_sorted){
  __shared__ float bl[HOPS*64*NH];
  for(int i=threadIdx.x; i<HOPS*64*NH; i+=256) bl[i] = b_edge[i];
  __syncthreads();
  int pos = blockIdx.x*256 + threadIdx.x;
  if(pos >= E_EDGES) return;
  int e = csr_eid[pos];
  const float* ef = edge_fts + (size_t)e*64;
  float acc[HOPS*NH];
  #pragma unroll
  for(int i=0;i<HOPS*NH;i++) acc[i]=0.f;
  for(int c=0; c<64; c+=4){
    float4 xv = *(const float4*)(ef + c);
    float x[4] = {xv.x, xv.y, xv.z, xv.w};
    #pragma unroll
    for(int j=0;j<4;j++){
      float xc = x[j]; int cc = c+j;
      #pragma unroll
      for(int hh=0; hh<HOPS*NH; hh++){
        int hop = hh>>2, h = hh&3;
        acc[hh] += xc * bl[hop*256 + cc*4 + h];
      }
    }
  }
  #pragma unroll
  for(int hop=0; hop<HOPS; hop++){
    *(float4*)(ae_sorted + ((size_t)hop*E_EDGES + pos)*4) =
      make_float4(acc[hop*4+0], acc[hop*4+1], acc[hop*4+2], acc[hop*4+3]);
  }
}

// ---------------- proj GEMM: h_all[N,512](fp16) = x[N,128] @ W[128,512] ----------------
__global__ __launch_bounds__(256) void k_proj(const float* __restrict__ x, const float* __restrict__ W,
                       __half* __restrict__ h_all){
  __shared__ float Asm[64][132];
  __shared__ float Bsm[128][64];
  int t = threadIdx.x;
  int row0 = blockIdx.x*64;
  int col0 = blockIdx.y*64;
  {
    int r = t>>5;           // 0..7
    int k4 = (t&31)<<2;     // 0..124
    #pragma unroll
    for(int rr=0; rr<64; rr+=8){
      int row = row0 + rr + r;
      float4 v = make_float4(0.f,0.f,0.f,0.f);
      if(row < N_NODES) v = *(const float4*)(x + (size_t)row*128 + k4);
      *(float4*)&Asm[rr+r][k4] = v;
    }
  }
  {
    int kr = t>>4;          // 0..15
    int c4 = (t&15)<<2;     // 0..60
    #pragma unroll
    for(int kk=0; kk<128; kk+=16){
      float4 u = *(const float4*)(W + (size_t)(kk+kr)*512 + col0 + c4);
      *(float4*)&Bsm[kk+kr][c4] = u;
    }
  }
  __syncthreads();
  int tr = t>>4, tc = t&15;
  int r0 = tr<<2, c0 = tc<<2;
  float acc[4][4] = {};
  #pragma unroll 4
  for(int k=0; k<128; k++){
    float a[4];
    #pragma unroll
    for(int i=0;i<4;i++) a[i] = Asm[r0+i][k];
    float4 bv = *(const float4*)&Bsm[k][c0];
    float b[4] = {bv.x, bv.y, bv.z, bv.w};
    #pragma unroll
    for(int i=0;i<4;i++)
      #pragma unroll
      for(int j=0;j<4;j++) acc[i][j] += a[i]*b[j];
  }
  #pragma unroll
  for(int i=0;i<4;i++){
    int row = row0 + r0 + i;
    if(row < N_NODES){
      __half2 p0 = __floats2half2_rn(acc[i][0], acc[i][1]);
      __half2 p1 = __floats2half2_rn(acc[i][2], acc[i][3]);
      uint2 wv;
      wv.x = *(unsigned int*)&p0;
      wv.y = *(unsigned int*)&p1;
      *(uint2*)(h_all + (size_t)row*512 + col0 + c0) = wv;
    }
  }
}

// ---------------- s_src[n,h], s_dst[n,h] ----------------
__global__ __launch_bounds__(256) void k_s(const __half* __restrict__ h_all, const float* __restrict__ asrc,
                    const float* __restrict__ adst, float* __restrict__ s_src, float* __restrict__ s_dst){
  int n = blockIdx.x; int t = threadIdx.x;
  int h = t>>6; int f0 = (t&63)<<1;
  __half2 hv2 = *(const __half2*)(h_all + (size_t)n*512 + (h<<7) + f0);
  float2 hv = __half22float2(hv2);
  int ai = (h<<7) + f0;
  float ps = hv.x*asrc[ai] + hv.y*asrc[ai+1];
  float pd = hv.x*adst[ai] + hv.y*adst[ai+1];
  #pragma unroll
  for(int off=32; off; off>>=1){ ps += __shfl_xor(ps,off); pd += __shfl_xor(pd,off); }
  if((t&63)==0){ s_src[n*4+h] = ps; s_dst[n*4+h] = pd; }
}

// ---------------- fused per-node softmax + aggregate ----------------
__global__ __launch_bounds__(256) void k_softagg(
    const float* __restrict__ ae, const float* __restrict__ s_src,
    const float* __restrict__ s_dst, const int* __restrict__ sorted_src,
    const int* __restrict__ row_ptr, const __half* __restrict__ h_all,
    float* __restrict__ ew_fb, float* __restrict__ xout)
{
  __shared__ float ws[MAXD*4];   // softmax weights per (slot, head)
  __shared__ int   ssm[MAXD];    // cached src ids
  __shared__ float red[512];
  __shared__ float mred[4][4];   // per-wave max partials
  __shared__ float sred[4][4];   // per-wave sum partials

  int n = blockIdx.x, t = threadIdx.x;
  int start = row_ptr[n], end = row_ptr[n+1];
  int deg = end - start;
  bool fits = (deg <= MAXD);
  int wv = t>>6, lane = t&63;

  float4 sd = *(const float4*)(s_dst + (size_t)n*4);
  float m0=-1e30f, m1=-1e30f, m2=-1e30f, m3=-1e30f;
  float aR[2][4];

  // ---- phase A: logits + per-thread max ----
  if(fits){
    #pragma unroll
    for(int k=0;k<2;k++){
      int pos = start + t + k*256;
      if(pos < end){
        int s = sorted_src[pos];
        float4 ss = *(const float4*)(s_src + (size_t)s*4);
        float4 av = *(const float4*)(ae + (size_t)pos*4);
        float a0 = ss.x+sd.x+av.x; a0=(a0>0.f)?a0:0.2f*a0;
        float a1 = ss.y+sd.y+av.y; a1=(a1>0.f)?a1:0.2f*a1;
        float a2 = ss.z+sd.z+av.z; a2=(a2>0.f)?a2:0.2f*a2;
        float a3 = ss.w+sd.w+av.w; a3=(a3>0.f)?a3:0.2f*a3;
        aR[k][0]=a0; aR[k][1]=a1; aR[k][2]=a2; aR[k][3]=a3;
        ssm[t + k*256] = s;
        m0=fmaxf(m0,a0); m1=fmaxf(m1,a1); m2=fmaxf(m2,a2); m3=fmaxf(m3,a3);
      }
    }
  } else {
    for(int pos=start+t; pos<end; pos+=256){
      int s = sorted_src[pos];
      float4 ss = *(const float4*)(s_src + (size_t)s*4);
      float4 av = *(const float4*)(ae + (size_t)pos*4);
      float a0 = ss.x+sd.x+av.x; a0=(a0>0.f)?a0:0.2f*a0;
      float a1 = ss.y+sd.y+av.y; a1=(a1>0.f)?a1:0.2f*a1;
      float a2 = ss.z+sd.z+av.z; a2=(a2>0.f)?a2:0.2f*a2;
      float a3 = ss.w+sd.w+av.w; a3=(a3>0.f)?a3:0.2f*a3;
      *(float4*)(ew_fb + (size_t)pos*4) = make_float4(a0,a1,a2,a3);
      m0=fmaxf(m0,a0); m1=fmaxf(m1,a1); m2=fmaxf(m2,a2); m3=fmaxf(m3,a3);
    }
  }
  #pragma unroll
  for(int off=32; off; off>>=1){
    m0=fmaxf(m0,__shfl_xor(m0,off)); m1=fmaxf(m1,__shfl_xor(m1,off));
    m2=fmaxf(m2,__shfl_xor(m2,off)); m3=fmaxf(m3,__shfl_xor(m3,off));
  }
  if(lane==0){ mred[wv][0]=m0; mred[wv][1]=m1; mred[wv][2]=m2; mred[wv][3]=m3; }
  __syncthreads();
  m0 = fmaxf(fmaxf(mred[0][0],mred[1][0]),fmaxf(mred[2][0],mred[3][0]));
  m1 = fmaxf(fmaxf(mred[0][1],mred[1][1]),fmaxf(mred[2][1],mred[3][1]));
  m2 = fmaxf(fmaxf(mred[0][2],mred[1][2]),fmaxf(mred[2][2],mred[3][2]));
  m3 = fmaxf(fmaxf(mred[0][3],mred[1][3]),fmaxf(mred[2][3],mred[3][3]));

  // ---- phase exp + sum ----
  float s0=0.f,s1=0.f,s2=0.f,s3=0.f;
  if(fits){
    #pragma unroll
    for(int k=0;k<2;k++){
      int pos = start + t + k*256;
      if(pos < end){
        float w0=__expf(aR[k][0]-m0), w1=__expf(aR[k][1]-m1);
        float w2=__expf(aR[k][2]-m2), w3=__expf(aR[k][3]-m3);
        int sl = (t + k*256)*4;
        ws[sl]=w0; ws[sl+1]=w1; ws[sl+2]=w2; ws[sl+3]=w3;
        s0+=w0; s1+=w1; s2+=w2; s3+=w3;
      }
    }
  } else {
    for(int pos=start+t; pos<end; pos+=256){
      float4 a = *(const float4*)(ew_fb + (size_t)pos*4);
      float w0=__expf(a.x-m0), w1=__expf(a.y-m1), w2=__expf(a.z-m2), w3=__expf(a.w-m3);
      *(float4*)(ew_fb + (size_t)pos*4) = make_float4(w0,w1,w2,w3);
      s0+=w0; s1+=w1; s2+=w2; s3+=w3;
    }
  }
  #pragma unroll
  for(int off=32; off; off>>=1){
    s0+=__shfl_xor(s0,off); s1+=__shfl_xor(s1,off);
    s2+=__shfl_xor(s2,off); s3+=__shfl_xor(s3,off);
  }
  if(lane==0){ sred[wv][0]=s0; sred[wv][1]=s1; sred[wv][2]=s2; sred[wv][3]=s3; }
  __syncthreads();

  // ---- phase B: weighted gather-aggregate, 4 edges in flight ----
  int slot = t>>6;           // 0..3 (== wave)
  int l = t&63;
  int h = l>>4;              // 0..3
  int f8 = (l&15)*8;         // 0..120
  float dh = sred[0][h]+sred[1][h]+sred[2][h]+sred[3][h];
  float inv = 1.f/(dh + 1e-16f);
  float acc[8] = {0.f,0.f,0.f,0.f,0.f,0.f,0.f,0.f};
  for(int p = start + slot; p < end; p += 4){
    int sl = p - start;
    int s; float w;
    if(fits){ s = ssm[sl]; w = ws[sl*4 + h]; }
    else    { s = sorted_src[p]; w = ew_fb[(size_t)p*4 + h]; }
    const __half* hp = h_all + (size_t)s*512 + (h<<7) + f8;
    float4 raw = *(const float4*)hp;      // 8 halves
    const __half2* hh = (const __half2*)&raw;
    float2 c0 = __half22float2(hh[0]);
    float2 c1 = __half22float2(hh[1]);
    float2 c2 = __half22float2(hh[2]);
    float2 c3 = __half22float2(hh[3]);
    acc[0]+=w*c0.x; acc[1]+=w*c0.y; acc[2]+=w*c1.x; acc[3]+=w*c1.y;
    acc[4]+=w*c2.x; acc[5]+=w*c2.y; acc[6]+=w*c3.x; acc[7]+=w*c3.y;
  }
  #pragma unroll
  for(int i=0;i<8;i++) acc[i]*=inv;
  int flat = (h<<7) + f8;
  if(slot==0){
    #pragma unroll
    for(int i=0;i<8;i++) red[flat+i] = acc[i];
  }
  __syncthreads();
  #pragma unroll
  for(int sg=1; sg<4; sg++){
    if(slot==sg){
      #pragma unroll
      for(int i=0;i<8;i++) red[flat+i] += acc[i];
    }
    __syncthreads();
  }
  if(t < 128){
    float v = 0.25f*(red[t] + red[128+t] + red[256+t] + red[384+t]);
    xout[(size_t)n*128 + t] = v;
  }
}

// ---------------- gated residual ----------------
__global__ __launch_bounds__(128) void k_gate(const float* __restrict__ prior, const float* __restrict__ curr,
                       const float* __restrict__ Wp, const float* __restrict__ Wc,
                       float* __restrict__ xnew){
  __shared__ float pr[128], cu[128];
  int n = blockIdx.x; int t = threadIdx.x;
  pr[t] = prior[(size_t)n*128 + t];
  cu[t] = curr[(size_t)n*128 + t];
  __syncthreads();
  float accp=0.f, accc=0.f;
  #pragma unroll 4
  for(int k=0; k<128; k++){
    accp += pr[k] * Wp[(size_t)k*128 + t];
    accc += cu[k] * Wc[(size_t)k*128 + t];
  }
  float z = accp + accc;
  float g = 1.f/(1.f + __expf(-z));
  xnew[(size_t)n*128 + t] = g*cu[t] + (1.f-g)*pr[t];
}

extern "C" void kernel_launch(void* const* d_in, const int* in_sizes, int n_in,
                              void* d_out, int out_size, void* d_ws, size_t ws_size,
                              hipStream_t stream){
  (void)in_sizes; (void)n_in; (void)out_size; (void)ws_size;
  const float* node_fts = (const float*)d_in[0];
  const float* edge_fts = (const float*)d_in[1];
  const int*   edges    = (const int*)d_in[2];
  const float* Ws       = (const float*)d_in[3];
  const float* Wes      = (const float*)d_in[4];
  const float* a_src    = (const float*)d_in[5];
  const float* a_dst    = (const float*)d_in[6];
  const float* a_edge   = (const float*)d_in[7];
  const float* W_prior  = (const float*)d_in[8];
  const float* W_curr   = (const float*)d_in[9];

  char* ws = (char*)d_ws;
  size_t off = 0;
  auto alloc = [&](size_t bytes)->void*{
    void* p = ws + off;
    off += (bytes + 255) & ~(size_t)255;
    return p;
  };
  int*    counts     = (int*)   alloc((size_t)N_NODES*4);
  int*    row_ptr    = (int*)   alloc((size_t)(N_NODES+1)*4);
  int*    fillp      = (int*)   alloc((size_t)N_NODES*4);
  int*    csr_eid    = (int*)   alloc((size_t)E_EDGES*4);
  int*    sorted_src = (int*)   alloc((size_t)E_EDGES*4);
  float*  b_edge     = (float*) alloc((size_t)HOPS*64*NH*4);
  float*  ae_sorted  = (float*) alloc((size_t)HOPS*E_EDGES*NH*4);
  __half* h_all      = (__half*)alloc((size_t)N_NODES*512*2);
  float*  s_src      = (float*) alloc((size_t)N_NODES*NH*4);
  float*  s_dst      = (float*) alloc((size_t)N_NODES*NH*4);
  float*  ew_fb      = (float*) alloc((size_t)E_EDGES*NH*4);
  float*  xbuf       = (float*) alloc((size_t)N_NODES*128*4);
  float*  curbuf     = (float*) alloc((size_t)N_NODES*128*4);

  const int* src = edges;
  const int* dst = edges + E_EDGES;

  (void)hipMemsetAsync(counts, 0, (size_t)N_NODES*4, stream);
  k_count<<<(E_EDGES+255)/256, 256, 0, stream>>>(dst, counts);
  k_scan<<<1, 1024, 0, stream>>>(counts, row_ptr, fillp);
  k_fill<<<(E_EDGES+255)/256, 256, 0, stream>>>(src, dst, fillp, csr_eid, sorted_src);
  k_bedge<<<3, 256, 0, stream>>>(Wes, a_edge, b_edge);
  k_alpha_e<<<(E_EDGES+255)/256, 256, 0, stream>>>(edge_fts, csr_eid, b_edge, ae_sorted);

  for(int hop=0; hop<HOPS; hop++){
    const float* xin = (hop==0) ? node_fts : xbuf;
    k_proj<<<dim3((N_NODES+63)/64, 8), 256, 0, stream>>>(xin, Ws + (size_t)hop*128*512, h_all);
    k_s<<<N_NODES, 256, 0, stream>>>(h_all, a_src + (size_t)hop*512, a_dst + (size_t)hop*512, s_src, s_dst);
    float* xout = (hop==0) ? xbuf : curbuf;
    k_softagg<<<N_NODES, 256, 0, stream>>>(ae_sorted + (size_t)hop*E_EDGES*4, s_src, s_dst,
                                           sorted_src, row_ptr, h_all, ew_fb, xout);
    if(hop > 0){
      float* xnew = (hop == HOPS-1) ? (float*)d_out : xbuf;
      k_gate<<<N_NODES, 128, 0, stream>>>(xbuf, curbuf, W_prior, W_curr, xnew);
    }
  }
}

// Round 5
// 360.354 us; speedup vs baseline: 1.6163x; 1.1709x over previous
//
#include <hip/hip_runtime.h>
#include <hip/hip_fp16.h>

#define N_NODES 10000
#define E_EDGES 320000
#define NH 4
#define HOPS 3
#define MAXD 512

typedef _Float16 f16x8 __attribute__((ext_vector_type(8)));
typedef _Float16 f16x4 __attribute__((ext_vector_type(4)));
typedef float    f32x4 __attribute__((ext_vector_type(4)));

// ---------------- CSR build ----------------
__global__ void k_count(const int* __restrict__ dst, int* __restrict__ counts){
  int e = blockIdx.x*256 + threadIdx.x;
  if(e < E_EDGES) atomicAdd(&counts[dst[e]], 1);
}

__global__ __launch_bounds__(1024) void k_scan(const int* __restrict__ counts,
                                               int* __restrict__ row_ptr, int* __restrict__ fillp){
  __shared__ int sm[1024];
  int t = threadIdx.x;
  const int CH = 10;
  int base = t*CH;
  int loc[CH]; int sum = 0;
  #pragma unroll
  for(int i=0;i<CH;i++){
    int v = (base+i < N_NODES) ? counts[base+i] : 0;
    loc[i] = sum; sum += v;
  }
  sm[t] = sum; __syncthreads();
  for(int off=1; off<1024; off<<=1){
    int add = (t>=off) ? sm[t-off] : 0;
    __syncthreads();
    sm[t] += add;
    __syncthreads();
  }
  int excl = (t>0) ? sm[t-1] : 0;
  #pragma unroll
  for(int i=0;i<CH;i++){
    int n = base+i;
    if(n < N_NODES){
      int e = excl + loc[i];
      row_ptr[n] = e;
      fillp[n]   = e;
    }
  }
  if(t==1023) row_ptr[N_NODES] = sm[1023];
}

__global__ void k_fill(const int* __restrict__ src, const int* __restrict__ dst,
                       int* __restrict__ fillp, int* __restrict__ csr_eid, int* __restrict__ sorted_src){
  int e = blockIdx.x*256 + threadIdx.x;
  if(e < E_EDGES){
    int d = dst[e];
    int pos = atomicAdd(&fillp[d], 1);
    csr_eid[pos] = e;
    sorted_src[pos] = src[e];
  }
}

// ---------------- b_edge[hop][c][h] ----------------
__global__ void k_bedge(const float* __restrict__ Wes, const float* __restrict__ a_edge,
                        float* __restrict__ b_edge){
  int idx = blockIdx.x*256 + threadIdx.x;
  if(idx >= HOPS*64*NH) return;
  int hop = idx/(64*NH); int c = (idx/NH)%64; int h = idx%NH;
  const float* we = Wes + (size_t)hop*64*512 + (size_t)c*512 + h*128;
  const float* ae = a_edge + (size_t)hop*NH*128 + h*128;
  float s = 0.f;
  for(int f=0; f<128; f++) s += we[f] * ae[f];
  b_edge[idx] = s;
}

// ---------------- alpha_e for all hops, CSR order ----------------
__global__ __launch_bounds__(256) void k_alpha_e(const float* __restrict__ edge_fts,
                        const int* __restrict__ csr_eid, const float* __restrict__ b_edge,
                        float* __restrict__ ae_sorted){
  __shared__ float bl[HOPS*64*NH];
  for(int i=threadIdx.x; i<HOPS*64*NH; i+=256) bl[i] = b_edge[i];
  __syncthreads();
  int pos = blockIdx.x*256 + threadIdx.x;
  if(pos >= E_EDGES) return;
  int e = csr_eid[pos];
  const float* ef = edge_fts + (size_t)e*64;
  float acc[HOPS*NH];
  #pragma unroll
  for(int i=0;i<HOPS*NH;i++) acc[i]=0.f;
  for(int c=0; c<64; c+=4){
    float4 xv = *(const float4*)(ef + c);
    float x[4] = {xv.x, xv.y, xv.z, xv.w};
    #pragma unroll
    for(int j=0;j<4;j++){
      float xc = x[j]; int cc = c+j;
      #pragma unroll
      for(int hh=0; hh<HOPS*NH; hh++){
        int hop = hh>>2, h = hh&3;
        acc[hh] += xc * bl[hop*256 + cc*4 + h];
      }
    }
  }
  #pragma unroll
  for(int hop=0; hop<HOPS; hop++){
    *(float4*)(ae_sorted + ((size_t)hop*E_EDGES + pos)*4) =
      make_float4(acc[hop*4+0], acc[hop*4+1], acc[hop*4+2], acc[hop*4+3]);
  }
}

// ---------------- setup: node_fts f32 -> xh f16 ----------------
__global__ void k_xh0(const float* __restrict__ in, _Float16* __restrict__ out){
  int i = blockIdx.x*256 + threadIdx.x;         // float4 units, 320000 total
  float4 v = *(const float4*)(in + (size_t)i*4);
  f16x4 h = { (_Float16)v.x, (_Float16)v.y, (_Float16)v.z, (_Float16)v.w };
  *(f16x4*)(out + (size_t)i*4) = h;
}

// ---------------- setup: Ws [hop][k][c] f32 -> WsT [hop][c][k] f16 (LDS transpose)
__global__ __launch_bounds__(256) void k_wt(const float* __restrict__ Ws, _Float16* __restrict__ WsT){
  __shared__ float lds[32][65];
  int b = blockIdx.x;               // 96 blocks = 3 hops * 4 ktiles * 8 ctiles
  int hop = b>>5, rem = b&31, kt = rem>>3, ct = rem&7;
  int k0 = kt*32, c0 = ct*64;
  int t = threadIdx.x;
  const float* wsrc = Ws + (size_t)hop*65536;
  #pragma unroll
  for(int i=0;i<8;i++){
    int u = t + i*256;              // 2048 elems
    int kk = u>>6, cc = u&63;
    lds[kk][cc] = wsrc[(size_t)(k0+kk)*512 + c0 + cc];
  }
  __syncthreads();
  _Float16* wdst = WsT + (size_t)hop*512*128;
  #pragma unroll
  for(int i=0;i<2;i++){
    int u = t + i*256;              // 512 units of 4 halves
    int c = u>>3, kq = (u&7)*4;
    f16x4 h = { (_Float16)lds[kq][c], (_Float16)lds[kq+1][c],
                (_Float16)lds[kq+2][c], (_Float16)lds[kq+3][c] };
    *(f16x4*)(wdst + (size_t)(c0+c)*128 + k0 + kq) = h;
  }
}

// ---------------- MFMA proj: h_all[N,512](f16) = xh[N,128] @ W[128,512] ----------------
// A/B frags: 8 contiguous-k halves per lane (same k convention both sides ->
// any intra-fragment k-permutation cancels in the K-sum). C/D: col=lane&15,
// row=(lane>>4)*4+reg (m89-verified).
__global__ __launch_bounds__(256) void k_projm(const _Float16* __restrict__ xh,
                       const _Float16* __restrict__ Wt, __half* __restrict__ h_all){
  int w = threadIdx.x>>6, l = threadIdx.x&63;
  int row0 = blockIdx.x*64 + w*16;
  int col0 = blockIdx.y*64;
  int ar = l&15, ac = (l>>4)*8;
  f32x4 acc0 = {0.f,0.f,0.f,0.f}, acc1 = acc0, acc2 = acc0, acc3 = acc0;
  #pragma unroll
  for(int kk=0; kk<4; kk++){
    f16x8 a = *(const f16x8*)(xh + (size_t)(row0+ar)*128 + kk*32 + ac);
    f16x8 b0 = *(const f16x8*)(Wt + (size_t)(col0 +  0 + ar)*128 + kk*32 + ac);
    f16x8 b1 = *(const f16x8*)(Wt + (size_t)(col0 + 16 + ar)*128 + kk*32 + ac);
    f16x8 b2 = *(const f16x8*)(Wt + (size_t)(col0 + 32 + ar)*128 + kk*32 + ac);
    f16x8 b3 = *(const f16x8*)(Wt + (size_t)(col0 + 48 + ar)*128 + kk*32 + ac);
    acc0 = __builtin_amdgcn_mfma_f32_16x16x32_f16(a, b0, acc0, 0, 0, 0);
    acc1 = __builtin_amdgcn_mfma_f32_16x16x32_f16(a, b1, acc1, 0, 0, 0);
    acc2 = __builtin_amdgcn_mfma_f32_16x16x32_f16(a, b2, acc2, 0, 0, 0);
    acc3 = __builtin_amdgcn_mfma_f32_16x16x32_f16(a, b3, acc3, 0, 0, 0);
  }
  int crow = (l>>4)*4, ccol = l&15;
  #pragma unroll
  for(int r=0; r<4; r++){
    int row = row0 + crow + r;
    if(row < N_NODES){
      size_t base = (size_t)row*512 + col0 + ccol;
      h_all[base +  0] = __float2half(acc0[r]);
      h_all[base + 16] = __float2half(acc1[r]);
      h_all[base + 32] = __float2half(acc2[r]);
      h_all[base + 48] = __float2half(acc3[r]);
    }
  }
}

// ---------------- s_src[n,h], s_dst[n,h] ----------------
__global__ __launch_bounds__(256) void k_s(const __half* __restrict__ h_all, const float* __restrict__ asrc,
                    const float* __restrict__ adst, float* __restrict__ s_src, float* __restrict__ s_dst){
  int n = blockIdx.x; int t = threadIdx.x;
  int h = t>>6; int f0 = (t&63)<<1;
  __half2 hv2 = *(const __half2*)(h_all + (size_t)n*512 + (h<<7) + f0);
  float2 hv = __half22float2(hv2);
  int ai = (h<<7) + f0;
  float ps = hv.x*asrc[ai] + hv.y*asrc[ai+1];
  float pd = hv.x*adst[ai] + hv.y*adst[ai+1];
  #pragma unroll
  for(int off=32; off; off>>=1){ ps += __shfl_xor(ps,off); pd += __shfl_xor(pd,off); }
  if((t&63)==0){ s_src[n*4+h] = ps; s_dst[n*4+h] = pd; }
}

// ---------------- fused per-node softmax + aggregate ----------------
__global__ __launch_bounds__(256) void k_softagg(
    const float* __restrict__ ae, const float* __restrict__ s_src,
    const float* __restrict__ s_dst, const int* __restrict__ sorted_src,
    const int* __restrict__ row_ptr, const __half* __restrict__ h_all,
    float* __restrict__ ew_fb, float* __restrict__ xout, _Float16* __restrict__ xh)
{
  __shared__ float ws[MAXD*4];
  __shared__ int   ssm[MAXD];
  __shared__ float red[512];
  __shared__ float mred[4][4];
  __shared__ float sred[4][4];

  int n = blockIdx.x, t = threadIdx.x;
  int start = row_ptr[n], end = row_ptr[n+1];
  int deg = end - start;
  bool fits = (deg <= MAXD);
  int wv = t>>6, lane = t&63;

  float4 sd = *(const float4*)(s_dst + (size_t)n*4);
  float m0=-1e30f, m1=-1e30f, m2=-1e30f, m3=-1e30f;
  float aR[2][4];

  if(fits){
    #pragma unroll
    for(int k=0;k<2;k++){
      int pos = start + t + k*256;
      if(pos < end){
        int s = sorted_src[pos];
        float4 ss = *(const float4*)(s_src + (size_t)s*4);
        float4 av = *(const float4*)(ae + (size_t)pos*4);
        float a0 = ss.x+sd.x+av.x; a0=(a0>0.f)?a0:0.2f*a0;
        float a1 = ss.y+sd.y+av.y; a1=(a1>0.f)?a1:0.2f*a1;
        float a2 = ss.z+sd.z+av.z; a2=(a2>0.f)?a2:0.2f*a2;
        float a3 = ss.w+sd.w+av.w; a3=(a3>0.f)?a3:0.2f*a3;
        aR[k][0]=a0; aR[k][1]=a1; aR[k][2]=a2; aR[k][3]=a3;
        ssm[t + k*256] = s;
        m0=fmaxf(m0,a0); m1=fmaxf(m1,a1); m2=fmaxf(m2,a2); m3=fmaxf(m3,a3);
      }
    }
  } else {
    for(int pos=start+t; pos<end; pos+=256){
      int s = sorted_src[pos];
      float4 ss = *(const float4*)(s_src + (size_t)s*4);
      float4 av = *(const float4*)(ae + (size_t)pos*4);
      float a0 = ss.x+sd.x+av.x; a0=(a0>0.f)?a0:0.2f*a0;
      float a1 = ss.y+sd.y+av.y; a1=(a1>0.f)?a1:0.2f*a1;
      float a2 = ss.z+sd.z+av.z; a2=(a2>0.f)?a2:0.2f*a2;
      float a3 = ss.w+sd.w+av.w; a3=(a3>0.f)?a3:0.2f*a3;
      *(float4*)(ew_fb + (size_t)pos*4) = make_float4(a0,a1,a2,a3);
      m0=fmaxf(m0,a0); m1=fmaxf(m1,a1); m2=fmaxf(m2,a2); m3=fmaxf(m3,a3);
    }
  }
  #pragma unroll
  for(int off=32; off; off>>=1){
    m0=fmaxf(m0,__shfl_xor(m0,off)); m1=fmaxf(m1,__shfl_xor(m1,off));
    m2=fmaxf(m2,__shfl_xor(m2,off)); m3=fmaxf(m3,__shfl_xor(m3,off));
  }
  if(lane==0){ mred[wv][0]=m0; mred[wv][1]=m1; mred[wv][2]=m2; mred[wv][3]=m3; }
  __syncthreads();
  m0 = fmaxf(fmaxf(mred[0][0],mred[1][0]),fmaxf(mred[2][0],mred[3][0]));
  m1 = fmaxf(fmaxf(mred[0][1],mred[1][1]),fmaxf(mred[2][1],mred[3][1]));
  m2 = fmaxf(fmaxf(mred[0][2],mred[1][2]),fmaxf(mred[2][2],mred[3][2]));
  m3 = fmaxf(fmaxf(mred[0][3],mred[1][3]),fmaxf(mred[2][3],mred[3][3]));

  float s0=0.f,s1=0.f,s2=0.f,s3=0.f;
  if(fits){
    #pragma unroll
    for(int k=0;k<2;k++){
      int pos = start + t + k*256;
      if(pos < end){
        float w0=__expf(aR[k][0]-m0), w1=__expf(aR[k][1]-m1);
        float w2=__expf(aR[k][2]-m2), w3=__expf(aR[k][3]-m3);
        int sl = (t + k*256)*4;
        ws[sl]=w0; ws[sl+1]=w1; ws[sl+2]=w2; ws[sl+3]=w3;
        s0+=w0; s1+=w1; s2+=w2; s3+=w3;
      }
    }
  } else {
    for(int pos=start+t; pos<end; pos+=256){
      float4 a = *(const float4*)(ew_fb + (size_t)pos*4);
      float w0=__expf(a.x-m0), w1=__expf(a.y-m1), w2=__expf(a.z-m2), w3=__expf(a.w-m3);
      *(float4*)(ew_fb + (size_t)pos*4) = make_float4(w0,w1,w2,w3);
      s0+=w0; s1+=w1; s2+=w2; s3+=w3;
    }
  }
  #pragma unroll
  for(int off=32; off; off>>=1){
    s0+=__shfl_xor(s0,off); s1+=__shfl_xor(s1,off);
    s2+=__shfl_xor(s2,off); s3+=__shfl_xor(s3,off);
  }
  if(lane==0){ sred[wv][0]=s0; sred[wv][1]=s1; sred[wv][2]=s2; sred[wv][3]=s3; }
  __syncthreads();

  int slot = t>>6;
  int l = t&63;
  int h = l>>4;
  int f8 = (l&15)*8;
  float dh = sred[0][h]+sred[1][h]+sred[2][h]+sred[3][h];
  float inv = 1.f/(dh + 1e-16f);
  float acc[8] = {0.f,0.f,0.f,0.f,0.f,0.f,0.f,0.f};
  for(int p = start + slot; p < end; p += 4){
    int sl = p - start;
    int s; float w;
    if(fits){ s = ssm[sl]; w = ws[sl*4 + h]; }
    else    { s = sorted_src[p]; w = ew_fb[(size_t)p*4 + h]; }
    const __half* hp = h_all + (size_t)s*512 + (h<<7) + f8;
    float4 raw = *(const float4*)hp;
    const __half2* hh = (const __half2*)&raw;
    float2 c0 = __half22float2(hh[0]);
    float2 c1 = __half22float2(hh[1]);
    float2 c2 = __half22float2(hh[2]);
    float2 c3 = __half22float2(hh[3]);
    acc[0]+=w*c0.x; acc[1]+=w*c0.y; acc[2]+=w*c1.x; acc[3]+=w*c1.y;
    acc[4]+=w*c2.x; acc[5]+=w*c2.y; acc[6]+=w*c3.x; acc[7]+=w*c3.y;
  }
  #pragma unroll
  for(int i=0;i<8;i++) acc[i]*=inv;
  int flat = (h<<7) + f8;
  if(slot==0){
    #pragma unroll
    for(int i=0;i<8;i++) red[flat+i] = acc[i];
  }
  __syncthreads();
  #pragma unroll
  for(int sg=1; sg<4; sg++){
    if(slot==sg){
      #pragma unroll
      for(int i=0;i<8;i++) red[flat+i] += acc[i];
    }
    __syncthreads();
  }
  if(t < 128){
    float v = 0.25f*(red[t] + red[128+t] + red[256+t] + red[384+t]);
    xout[(size_t)n*128 + t] = v;
    if(xh) xh[(size_t)n*128 + t] = (_Float16)v;
  }
}

// ---------------- gated residual, GEMM-tiled: 32 nodes x 64 cols per block ----------------
__global__ __launch_bounds__(256) void k_gate2(const float* __restrict__ prior, const float* __restrict__ curr,
                       const float* __restrict__ Wp, const float* __restrict__ Wc,
                       float* __restrict__ xnew, _Float16* __restrict__ xh){
  __shared__ float pr[32][132];
  __shared__ float cu[32][132];
  int t = threadIdx.x;
  int n0 = blockIdx.x*32;
  int c0 = blockIdx.y*64;
  #pragma unroll
  for(int i=0;i<4;i++){
    int u = t + i*256;                 // 1024 float4 units
    int row = u>>5, c4 = (u&31)<<2;
    float4 v = make_float4(0.f,0.f,0.f,0.f), w = v;
    if(n0+row < N_NODES){
      v = *(const float4*)(prior + (size_t)(n0+row)*128 + c4);
      w = *(const float4*)(curr  + (size_t)(n0+row)*128 + c4);
    }
    *(float4*)&pr[row][c4] = v;
    *(float4*)&cu[row][c4] = w;
  }
  __syncthreads();
  int tc = t&15, tr = t>>4;            // tr 0..15
  int r0 = tr*2, cc = c0 + tc*4;       // cc 0..127 local==global col
  float accp[2][4] = {{0.f,0.f,0.f,0.f},{0.f,0.f,0.f,0.f}};
  float accc[2][4] = {{0.f,0.f,0.f,0.f},{0.f,0.f,0.f,0.f}};
  #pragma unroll 4
  for(int k=0;k<128;k++){
    float4 wp = *(const float4*)(Wp + (size_t)k*128 + cc);
    float4 wc = *(const float4*)(Wc + (size_t)k*128 + cc);
    #pragma unroll
    for(int i=0;i<2;i++){
      float ap = pr[r0+i][k], ac = cu[r0+i][k];
      accp[i][0]+=ap*wp.x; accp[i][1]+=ap*wp.y; accp[i][2]+=ap*wp.z; accp[i][3]+=ap*wp.w;
      accc[i][0]+=ac*wc.x; accc[i][1]+=ac*wc.y; accc[i][2]+=ac*wc.z; accc[i][3]+=ac*wc.w;
    }
  }
  #pragma unroll
  for(int i=0;i<2;i++){
    int row = n0 + r0 + i;
    if(row < N_NODES){
      float oj[4];
      #pragma unroll
      for(int j=0;j<4;j++){
        float z = accp[i][j]+accc[i][j];
        float g = 1.f/(1.f+__expf(-z));
        oj[j] = g*cu[r0+i][cc - c0 + c0 + j] + (1.f-g)*pr[r0+i][cc + j];
      }
      *(float4*)(xnew + (size_t)row*128 + cc) = make_float4(oj[0],oj[1],oj[2],oj[3]);
      if(xh){
        f16x4 hv = { (_Float16)oj[0], (_Float16)oj[1], (_Float16)oj[2], (_Float16)oj[3] };
        *(f16x4*)(xh + (size_t)row*128 + cc) = hv;
      }
    }
  }
}

extern "C" void kernel_launch(void* const* d_in, const int* in_sizes, int n_in,
                              void* d_out, int out_size, void* d_ws, size_t ws_size,
                              hipStream_t stream){
  (void)in_sizes; (void)n_in; (void)out_size; (void)ws_size;
  const float* node_fts = (const float*)d_in[0];
  const float* edge_fts = (const float*)d_in[1];
  const int*   edges    = (const int*)d_in[2];
  const float* Ws       = (const float*)d_in[3];
  const float* Wes      = (const float*)d_in[4];
  const float* a_src    = (const float*)d_in[5];
  const float* a_dst    = (const float*)d_in[6];
  const float* a_edge   = (const float*)d_in[7];
  const float* W_prior  = (const float*)d_in[8];
  const float* W_curr   = (const float*)d_in[9];

  char* ws = (char*)d_ws;
  size_t off = 0;
  auto alloc = [&](size_t bytes)->void*{
    void* p = ws + off;
    off += (bytes + 255) & ~(size_t)255;
    return p;
  };
  int*       counts     = (int*)      alloc((size_t)N_NODES*4);
  int*       row_ptr    = (int*)      alloc((size_t)(N_NODES+1)*4);
  int*       fillp      = (int*)      alloc((size_t)N_NODES*4);
  int*       csr_eid    = (int*)      alloc((size_t)E_EDGES*4);
  int*       sorted_src = (int*)      alloc((size_t)E_EDGES*4);
  float*     b_edge     = (float*)    alloc((size_t)HOPS*64*NH*4);
  float*     ae_sorted  = (float*)    alloc((size_t)HOPS*E_EDGES*NH*4);
  __half*    h_all      = (__half*)   alloc((size_t)N_NODES*512*2);
  float*     s_src      = (float*)    alloc((size_t)N_NODES*NH*4);
  float*     s_dst      = (float*)    alloc((size_t)N_NODES*NH*4);
  float*     ew_fb      = (float*)    alloc((size_t)E_EDGES*NH*4);
  float*     xbuf       = (float*)    alloc((size_t)N_NODES*128*4);
  float*     curbuf     = (float*)    alloc((size_t)N_NODES*128*4);
  _Float16*  xh         = (_Float16*) alloc((size_t)10112*128*2);   // padded rows for MFMA over-read
  _Float16*  WsT        = (_Float16*) alloc((size_t)HOPS*512*128*2);

  const int* src = edges;
  const int* dst = edges + E_EDGES;

  (void)hipMemsetAsync(counts, 0, (size_t)N_NODES*4, stream);
  k_count<<<(E_EDGES+255)/256, 256, 0, stream>>>(dst, counts);
  k_scan<<<1, 1024, 0, stream>>>(counts, row_ptr, fillp);
  k_fill<<<(E_EDGES+255)/256, 256, 0, stream>>>(src, dst, fillp, csr_eid, sorted_src);
  k_bedge<<<3, 256, 0, stream>>>(Wes, a_edge, b_edge);
  k_alpha_e<<<(E_EDGES+255)/256, 256, 0, stream>>>(edge_fts, csr_eid, b_edge, ae_sorted);
  k_wt<<<96, 256, 0, stream>>>(Ws, WsT);
  k_xh0<<<1250, 256, 0, stream>>>(node_fts, xh);    // 1250*256*4 = 1,280,000 elems exact

  for(int hop=0; hop<HOPS; hop++){
    k_projm<<<dim3(157, 8), 256, 0, stream>>>(xh, WsT + (size_t)hop*512*128, h_all);
    k_s<<<N_NODES, 256, 0, stream>>>(h_all, a_src + (size_t)hop*512, a_dst + (size_t)hop*512, s_src, s_dst);
    float* xout = (hop==0) ? xbuf : curbuf;
    k_softagg<<<N_NODES, 256, 0, stream>>>(ae_sorted + (size_t)hop*E_EDGES*4, s_src, s_dst,
                                           sorted_src, row_ptr, h_all, ew_fb, xout,
                                           (hop==0) ? xh : (_Float16*)nullptr);
    if(hop > 0){
      float* xnew = (hop == HOPS-1) ? (float*)d_out : xbuf;
      k_gate2<<<dim3(313, 2), 256, 0, stream>>>(xbuf, curbuf, W_prior, W_curr, xnew,
                                                (hop < HOPS-1) ? xh : (_Float16*)nullptr);
    }
  }
}

// Round 6
// 346.067 us; speedup vs baseline: 1.6830x; 1.0413x over previous
//
#include <hip/hip_runtime.h>
#include <hip/hip_fp16.h>

#define N_NODES 10000
#define E_EDGES 320000
#define NH 4
#define HOPS 3
#define MAXD 256

typedef _Float16 f16x8 __attribute__((ext_vector_type(8)));
typedef _Float16 f16x4 __attribute__((ext_vector_type(4)));
typedef float    f32x4 __attribute__((ext_vector_type(4)));

// ---------------- CSR build ----------------
__global__ void k_count(const int* __restrict__ dst, int* __restrict__ counts){
  int e = blockIdx.x*256 + threadIdx.x;
  if(e < E_EDGES) atomicAdd(&counts[dst[e]], 1);
}

__global__ __launch_bounds__(1024) void k_scan(const int* __restrict__ counts,
                                               int* __restrict__ row_ptr, int* __restrict__ fillp){
  __shared__ int sm[1024];
  int t = threadIdx.x;
  const int CH = 10;
  int base = t*CH;
  int loc[CH]; int sum = 0;
  #pragma unroll
  for(int i=0;i<CH;i++){
    int v = (base+i < N_NODES) ? counts[base+i] : 0;
    loc[i] = sum; sum += v;
  }
  sm[t] = sum; __syncthreads();
  for(int off=1; off<1024; off<<=1){
    int add = (t>=off) ? sm[t-off] : 0;
    __syncthreads();
    sm[t] += add;
    __syncthreads();
  }
  int excl = (t>0) ? sm[t-1] : 0;
  #pragma unroll
  for(int i=0;i<CH;i++){
    int n = base+i;
    if(n < N_NODES){
      int e = excl + loc[i];
      row_ptr[n] = e;
      fillp[n]   = e;
    }
  }
  if(t==1023) row_ptr[N_NODES] = sm[1023];
}

// also records pos_e[e] = CSR slot of edge e (inverse permutation)
__global__ void k_fill(const int* __restrict__ src, const int* __restrict__ dst,
                       int* __restrict__ fillp, int* __restrict__ pos_e, int* __restrict__ sorted_src){
  int e = blockIdx.x*256 + threadIdx.x;
  if(e < E_EDGES){
    int d = dst[e];
    int pos = atomicAdd(&fillp[d], 1);
    pos_e[e] = pos;
    sorted_src[pos] = src[e];
  }
}

// ---------------- merged setup: xh0 | WsT transpose | b_edge ----------------
__global__ __launch_bounds__(256) void k_setup(const float* __restrict__ node_fts, _Float16* __restrict__ xh,
                       const float* __restrict__ Ws, _Float16* __restrict__ WsT,
                       const float* __restrict__ Wes, const float* __restrict__ a_edge,
                       float* __restrict__ b_edge){
  __shared__ float lds[32][65];
  int b = blockIdx.x, t = threadIdx.x;
  if(b < 1250){
    int i = b*256 + t;                 // float4 units, 320000 total
    float4 v = *(const float4*)(node_fts + (size_t)i*4);
    f16x4 h = { (_Float16)v.x, (_Float16)v.y, (_Float16)v.z, (_Float16)v.w };
    *(f16x4*)(xh + (size_t)i*4) = h;
  } else if(b < 1346){
    int b2 = b - 1250;                 // 96 blocks = 3 hops * 4 ktiles * 8 ctiles
    int hop = b2>>5, rem = b2&31, kt = rem>>3, ct = rem&7;
    int k0 = kt*32, c0 = ct*64;
    const float* wsrc = Ws + (size_t)hop*65536;
    #pragma unroll
    for(int i=0;i<8;i++){
      int u = t + i*256;
      int kk = u>>6, cc = u&63;
      lds[kk][cc] = wsrc[(size_t)(k0+kk)*512 + c0 + cc];
    }
    __syncthreads();
    _Float16* wdst = WsT + (size_t)hop*512*128;
    #pragma unroll
    for(int i=0;i<2;i++){
      int u = t + i*256;
      int c = u>>3, kq = (u&7)*4;
      f16x4 h = { (_Float16)lds[kq][c], (_Float16)lds[kq+1][c],
                  (_Float16)lds[kq+2][c], (_Float16)lds[kq+3][c] };
      *(f16x4*)(wdst + (size_t)(c0+c)*128 + k0 + kq) = h;
    }
  } else {
    int idx = (b-1346)*256 + t;
    if(idx < HOPS*64*NH){
      int hop = idx/(64*NH); int c = (idx/NH)%64; int h = idx%NH;
      const float* we = Wes + (size_t)hop*64*512 + (size_t)c*512 + h*128;
      const float* ae = a_edge + (size_t)hop*NH*128 + h*128;
      float s = 0.f;
      for(int f=0; f<128; f++) s += we[f] * ae[f];
      b_edge[idx] = s;
    }
  }
}

// ---------------- alpha_e: NATURAL edge order (coalesced read), scatter write ----------------
__global__ __launch_bounds__(256) void k_alpha_e(const float* __restrict__ edge_fts,
                        const int* __restrict__ pos_e, const float* __restrict__ b_edge,
                        float* __restrict__ ae_sorted){
  __shared__ float bl[HOPS*64*NH];
  for(int i=threadIdx.x; i<HOPS*64*NH; i+=256) bl[i] = b_edge[i];
  __syncthreads();
  int e = blockIdx.x*256 + threadIdx.x;
  if(e >= E_EDGES) return;
  int pos = pos_e[e];
  const float* ef = edge_fts + (size_t)e*64;
  float acc[HOPS*NH];
  #pragma unroll
  for(int i=0;i<HOPS*NH;i++) acc[i]=0.f;
  for(int c=0; c<64; c+=4){
    float4 xv = *(const float4*)(ef + c);
    float x[4] = {xv.x, xv.y, xv.z, xv.w};
    #pragma unroll
    for(int j=0;j<4;j++){
      float xc = x[j]; int cc = c+j;
      #pragma unroll
      for(int hh=0; hh<HOPS*NH; hh++){
        int hop = hh>>2, h = hh&3;
        acc[hh] += xc * bl[hop*256 + cc*4 + h];
      }
    }
  }
  #pragma unroll
  for(int hop=0; hop<HOPS; hop++){
    *(float4*)(ae_sorted + ((size_t)hop*E_EDGES + pos)*4) =
      make_float4(acc[hop*4+0], acc[hop*4+1], acc[hop*4+2], acc[hop*4+3]);
  }
}

// ---------------- MFMA proj + LDS repack for coalesced stores ----------------
__global__ __launch_bounds__(256) void k_projm(const _Float16* __restrict__ xh,
                       const _Float16* __restrict__ Wt, __half* __restrict__ h_all){
  __shared__ __align__(16) __half tile[64][72];
  int w = threadIdx.x>>6, l = threadIdx.x&63;
  int rowb = blockIdx.x*64;
  int row0 = rowb + w*16;
  int col0 = blockIdx.y*64;
  int ar = l&15, ac = (l>>4)*8;
  f32x4 acc0 = {0.f,0.f,0.f,0.f}, acc1 = acc0, acc2 = acc0, acc3 = acc0;
  #pragma unroll
  for(int kk=0; kk<4; kk++){
    f16x8 a  = *(const f16x8*)(xh + (size_t)(row0+ar)*128 + kk*32 + ac);
    f16x8 b0 = *(const f16x8*)(Wt + (size_t)(col0 +  0 + ar)*128 + kk*32 + ac);
    f16x8 b1 = *(const f16x8*)(Wt + (size_t)(col0 + 16 + ar)*128 + kk*32 + ac);
    f16x8 b2 = *(const f16x8*)(Wt + (size_t)(col0 + 32 + ar)*128 + kk*32 + ac);
    f16x8 b3 = *(const f16x8*)(Wt + (size_t)(col0 + 48 + ar)*128 + kk*32 + ac);
    acc0 = __builtin_amdgcn_mfma_f32_16x16x32_f16(a, b0, acc0, 0, 0, 0);
    acc1 = __builtin_amdgcn_mfma_f32_16x16x32_f16(a, b1, acc1, 0, 0, 0);
    acc2 = __builtin_amdgcn_mfma_f32_16x16x32_f16(a, b2, acc2, 0, 0, 0);
    acc3 = __builtin_amdgcn_mfma_f32_16x16x32_f16(a, b3, acc3, 0, 0, 0);
  }
  int crow = (l>>4)*4, ccol = l&15;
  #pragma unroll
  for(int r=0; r<4; r++){
    int tr = w*16 + crow + r;
    tile[tr][ccol     ] = __float2half(acc0[r]);
    tile[tr][ccol + 16] = __float2half(acc1[r]);
    tile[tr][ccol + 32] = __float2half(acc2[r]);
    tile[tr][ccol + 48] = __float2half(acc3[r]);
  }
  __syncthreads();
  #pragma unroll
  for(int i=0;i<2;i++){
    int u = threadIdx.x + i*256;      // 512 float4 units = 64 rows x 8
    int row = u>>3, cq = (u&7)*8;
    int grow = rowb + row;
    if(grow < N_NODES)
      *(float4*)(h_all + (size_t)grow*512 + col0 + cq) = *(const float4*)&tile[row][cq];
  }
}

// ---------------- s_src/s_dst: wave per node ----------------
__global__ __launch_bounds__(256) void k_s(const __half* __restrict__ h_all, const float* __restrict__ asrc,
                    const float* __restrict__ adst, float* __restrict__ s_src, float* __restrict__ s_dst){
  int nw = blockIdx.x*4 + (threadIdx.x>>6);
  int l = threadIdx.x&63;
  if(nw >= N_NODES) return;
  int h = l>>4, f8 = (l&15)*8;
  const __half* hp = h_all + (size_t)nw*512 + (h<<7) + f8;
  float4 raw = *(const float4*)hp;
  const __half2* hh = (const __half2*)&raw;
  float2 c0 = __half22float2(hh[0]);
  float2 c1 = __half22float2(hh[1]);
  float2 c2 = __half22float2(hh[2]);
  float2 c3 = __half22float2(hh[3]);
  float4 a0 = *(const float4*)(asrc + (h<<7) + f8);
  float4 a1 = *(const float4*)(asrc + (h<<7) + f8 + 4);
  float4 d0 = *(const float4*)(adst + (h<<7) + f8);
  float4 d1 = *(const float4*)(adst + (h<<7) + f8 + 4);
  float ps = c0.x*a0.x + c0.y*a0.y + c1.x*a0.z + c1.y*a0.w
           + c2.x*a1.x + c2.y*a1.y + c3.x*a1.z + c3.y*a1.w;
  float pd = c0.x*d0.x + c0.y*d0.y + c1.x*d0.z + c1.y*d0.w
           + c2.x*d1.x + c2.y*d1.y + c3.x*d1.z + c3.y*d1.w;
  #pragma unroll
  for(int off=1; off<16; off<<=1){ ps += __shfl_xor(ps,off); pd += __shfl_xor(pd,off); }
  if((l&15)==0){ s_src[nw*4+h] = ps; s_dst[nw*4+h] = pd; }
}

// ---------------- fused per-node softmax + aggregate ----------------
__global__ __launch_bounds__(256) void k_softagg(
    const float* __restrict__ ae, const float* __restrict__ s_src,
    const float* __restrict__ s_dst, const int* __restrict__ sorted_src,
    const int* __restrict__ row_ptr, const __half* __restrict__ h_all,
    float* __restrict__ ew_fb, float* __restrict__ xout, _Float16* __restrict__ xh)
{
  __shared__ float ws[MAXD*4];     // 4 KB
  __shared__ int   ssm[MAXD];      // 1 KB
  __shared__ float red2[4][520];   // 8.3 KB, slot-private
  __shared__ float mred[4][4];
  __shared__ float sred[4][4];

  int n = blockIdx.x, t = threadIdx.x;
  int start = row_ptr[n], end = row_ptr[n+1];
  int deg = end - start;
  bool fits = (deg <= MAXD);
  int wv = t>>6, lane = t&63;

  float4 sd = *(const float4*)(s_dst + (size_t)n*4);
  float m0=-1e30f, m1=-1e30f, m2=-1e30f, m3=-1e30f;
  float aR[4];

  // ---- phase A: logits + per-thread max ----
  if(fits){
    if(t < deg){
      int pos = start + t;
      int s = sorted_src[pos];
      float4 ss = *(const float4*)(s_src + (size_t)s*4);
      float4 av = *(const float4*)(ae + (size_t)pos*4);
      float a0 = ss.x+sd.x+av.x; a0=(a0>0.f)?a0:0.2f*a0;
      float a1 = ss.y+sd.y+av.y; a1=(a1>0.f)?a1:0.2f*a1;
      float a2 = ss.z+sd.z+av.z; a2=(a2>0.f)?a2:0.2f*a2;
      float a3 = ss.w+sd.w+av.w; a3=(a3>0.f)?a3:0.2f*a3;
      aR[0]=a0; aR[1]=a1; aR[2]=a2; aR[3]=a3;
      ssm[t] = s;
      m0=a0; m1=a1; m2=a2; m3=a3;
    }
  } else {
    for(int pos=start+t; pos<end; pos+=256){
      int s = sorted_src[pos];
      float4 ss = *(const float4*)(s_src + (size_t)s*4);
      float4 av = *(const float4*)(ae + (size_t)pos*4);
      float a0 = ss.x+sd.x+av.x; a0=(a0>0.f)?a0:0.2f*a0;
      float a1 = ss.y+sd.y+av.y; a1=(a1>0.f)?a1:0.2f*a1;
      float a2 = ss.z+sd.z+av.z; a2=(a2>0.f)?a2:0.2f*a2;
      float a3 = ss.w+sd.w+av.w; a3=(a3>0.f)?a3:0.2f*a3;
      *(float4*)(ew_fb + (size_t)pos*4) = make_float4(a0,a1,a2,a3);
      m0=fmaxf(m0,a0); m1=fmaxf(m1,a1); m2=fmaxf(m2,a2); m3=fmaxf(m3,a3);
    }
  }
  #pragma unroll
  for(int off=32; off; off>>=1){
    m0=fmaxf(m0,__shfl_xor(m0,off)); m1=fmaxf(m1,__shfl_xor(m1,off));
    m2=fmaxf(m2,__shfl_xor(m2,off)); m3=fmaxf(m3,__shfl_xor(m3,off));
  }
  if(lane==0){ mred[wv][0]=m0; mred[wv][1]=m1; mred[wv][2]=m2; mred[wv][3]=m3; }
  __syncthreads();
  m0 = fmaxf(fmaxf(mred[0][0],mred[1][0]),fmaxf(mred[2][0],mred[3][0]));
  m1 = fmaxf(fmaxf(mred[0][1],mred[1][1]),fmaxf(mred[2][1],mred[3][1]));
  m2 = fmaxf(fmaxf(mred[0][2],mred[1][2]),fmaxf(mred[2][2],mred[3][2]));
  m3 = fmaxf(fmaxf(mred[0][3],mred[1][3]),fmaxf(mred[2][3],mred[3][3]));

  // ---- exp + sum ----
  float s0=0.f,s1=0.f,s2=0.f,s3=0.f;
  if(fits){
    if(t < deg){
      float w0=__expf(aR[0]-m0), w1=__expf(aR[1]-m1);
      float w2=__expf(aR[2]-m2), w3=__expf(aR[3]-m3);
      int sl = t*4;
      ws[sl]=w0; ws[sl+1]=w1; ws[sl+2]=w2; ws[sl+3]=w3;
      s0=w0; s1=w1; s2=w2; s3=w3;
    }
  } else {
    for(int pos=start+t; pos<end; pos+=256){
      float4 a = *(const float4*)(ew_fb + (size_t)pos*4);
      float w0=__expf(a.x-m0), w1=__expf(a.y-m1), w2=__expf(a.z-m2), w3=__expf(a.w-m3);
      *(float4*)(ew_fb + (size_t)pos*4) = make_float4(w0,w1,w2,w3);
      s0+=w0; s1+=w1; s2+=w2; s3+=w3;
    }
  }
  #pragma unroll
  for(int off=32; off; off>>=1){
    s0+=__shfl_xor(s0,off); s1+=__shfl_xor(s1,off);
    s2+=__shfl_xor(s2,off); s3+=__shfl_xor(s3,off);
  }
  if(lane==0){ sred[wv][0]=s0; sred[wv][1]=s1; sred[wv][2]=s2; sred[wv][3]=s3; }
  __syncthreads();

  // ---- phase B: weighted gather-aggregate, 4 edges in flight ----
  int slot = t>>6;
  int l = t&63;
  int h = l>>4;
  int f8 = (l&15)*8;
  float dh = sred[0][h]+sred[1][h]+sred[2][h]+sred[3][h];
  float inv = 1.f/(dh + 1e-16f);
  float acc[8] = {0.f,0.f,0.f,0.f,0.f,0.f,0.f,0.f};
  for(int p = start + slot; p < end; p += 4){
    int sl = p - start;
    int s; float w;
    if(fits){ s = ssm[sl]; w = ws[sl*4 + h]; }
    else    { s = sorted_src[p]; w = ew_fb[(size_t)p*4 + h]; }
    const __half* hp = h_all + (size_t)s*512 + (h<<7) + f8;
    float4 raw = *(const float4*)hp;
    const __half2* hh = (const __half2*)&raw;
    float2 c0 = __half22float2(hh[0]);
    float2 c1 = __half22float2(hh[1]);
    float2 c2 = __half22float2(hh[2]);
    float2 c3 = __half22float2(hh[3]);
    acc[0]+=w*c0.x; acc[1]+=w*c0.y; acc[2]+=w*c1.x; acc[3]+=w*c1.y;
    acc[4]+=w*c2.x; acc[5]+=w*c2.y; acc[6]+=w*c3.x; acc[7]+=w*c3.y;
  }
  int flat = (h<<7) + f8;
  #pragma unroll
  for(int i=0;i<8;i++) red2[slot][flat+i] = acc[i]*inv;
  __syncthreads();
  if(t < 128){
    float v = 0.f;
    #pragma unroll
    for(int s=0;s<4;s++)
      v += red2[s][t] + red2[s][128+t] + red2[s][256+t] + red2[s][384+t];
    v *= 0.25f;
    xout[(size_t)n*128 + t] = v;
    if(xh) xh[(size_t)n*128 + t] = (_Float16)v;
  }
}

// ---------------- gated residual, GEMM-tiled ----------------
__global__ __launch_bounds__(256) void k_gate2(const float* __restrict__ prior, const float* __restrict__ curr,
                       const float* __restrict__ Wp, const float* __restrict__ Wc,
                       float* __restrict__ xnew, _Float16* __restrict__ xh){
  __shared__ float pr[32][132];
  __shared__ float cu[32][132];
  int t = threadIdx.x;
  int n0 = blockIdx.x*32;
  int c0 = blockIdx.y*64;
  #pragma unroll
  for(int i=0;i<4;i++){
    int u = t + i*256;
    int row = u>>5, c4 = (u&31)<<2;
    float4 v = make_float4(0.f,0.f,0.f,0.f), w = v;
    if(n0+row < N_NODES){
      v = *(const float4*)(prior + (size_t)(n0+row)*128 + c4);
      w = *(const float4*)(curr  + (size_t)(n0+row)*128 + c4);
    }
    *(float4*)&pr[row][c4] = v;
    *(float4*)&cu[row][c4] = w;
  }
  __syncthreads();
  int tc = t&15, tr = t>>4;
  int r0 = tr*2, cc = c0 + tc*4;
  float accp[2][4] = {{0.f,0.f,0.f,0.f},{0.f,0.f,0.f,0.f}};
  float accc[2][4] = {{0.f,0.f,0.f,0.f},{0.f,0.f,0.f,0.f}};
  #pragma unroll 4
  for(int k=0;k<128;k++){
    float4 wp = *(const float4*)(Wp + (size_t)k*128 + cc);
    float4 wc = *(const float4*)(Wc + (size_t)k*128 + cc);
    #pragma unroll
    for(int i=0;i<2;i++){
      float ap = pr[r0+i][k], ac = cu[r0+i][k];
      accp[i][0]+=ap*wp.x; accp[i][1]+=ap*wp.y; accp[i][2]+=ap*wp.z; accp[i][3]+=ap*wp.w;
      accc[i][0]+=ac*wc.x; accc[i][1]+=ac*wc.y; accc[i][2]+=ac*wc.z; accc[i][3]+=ac*wc.w;
    }
  }
  #pragma unroll
  for(int i=0;i<2;i++){
    int row = n0 + r0 + i;
    if(row < N_NODES){
      float oj[4];
      #pragma unroll
      for(int j=0;j<4;j++){
        float z = accp[i][j]+accc[i][j];
        float g = 1.f/(1.f+__expf(-z));
        oj[j] = g*cu[r0+i][cc + j] + (1.f-g)*pr[r0+i][cc + j];
      }
      *(float4*)(xnew + (size_t)row*128 + cc) = make_float4(oj[0],oj[1],oj[2],oj[3]);
      if(xh){
        f16x4 hv = { (_Float16)oj[0], (_Float16)oj[1], (_Float16)oj[2], (_Float16)oj[3] };
        *(f16x4*)(xh + (size_t)row*128 + cc) = hv;
      }
    }
  }
}

extern "C" void kernel_launch(void* const* d_in, const int* in_sizes, int n_in,
                              void* d_out, int out_size, void* d_ws, size_t ws_size,
                              hipStream_t stream){
  (void)in_sizes; (void)n_in; (void)out_size; (void)ws_size;
  const float* node_fts = (const float*)d_in[0];
  const float* edge_fts = (const float*)d_in[1];
  const int*   edges    = (const int*)d_in[2];
  const float* Ws       = (const float*)d_in[3];
  const float* Wes      = (const float*)d_in[4];
  const float* a_src    = (const float*)d_in[5];
  const float* a_dst    = (const float*)d_in[6];
  const float* a_edge   = (const float*)d_in[7];
  const float* W_prior  = (const float*)d_in[8];
  const float* W_curr   = (const float*)d_in[9];

  char* ws = (char*)d_ws;
  size_t off = 0;
  auto alloc = [&](size_t bytes)->void*{
    void* p = ws + off;
    off += (bytes + 255) & ~(size_t)255;
    return p;
  };
  int*       counts     = (int*)      alloc((size_t)N_NODES*4);
  int*       row_ptr    = (int*)      alloc((size_t)(N_NODES+1)*4);
  int*       fillp      = (int*)      alloc((size_t)N_NODES*4);
  int*       pos_e      = (int*)      alloc((size_t)E_EDGES*4);
  int*       sorted_src = (int*)      alloc((size_t)E_EDGES*4);
  float*     b_edge     = (float*)    alloc((size_t)HOPS*64*NH*4);
  float*     ae_sorted  = (float*)    alloc((size_t)HOPS*E_EDGES*NH*4);
  __half*    h_all      = (__half*)   alloc((size_t)N_NODES*512*2);
  float*     s_src      = (float*)    alloc((size_t)N_NODES*NH*4);
  float*     s_dst      = (float*)    alloc((size_t)N_NODES*NH*4);
  float*     ew_fb      = (float*)    alloc((size_t)E_EDGES*NH*4);
  float*     xbuf       = (float*)    alloc((size_t)N_NODES*128*4);
  float*     curbuf     = (float*)    alloc((size_t)N_NODES*128*4);
  _Float16*  xh         = (_Float16*) alloc((size_t)10112*128*2);   // padded rows for MFMA over-read
  _Float16*  WsT        = (_Float16*) alloc((size_t)HOPS*512*128*2);

  const int* src = edges;
  const int* dst = edges + E_EDGES;

  (void)hipMemsetAsync(counts, 0, (size_t)N_NODES*4, stream);
  k_count<<<(E_EDGES+255)/256, 256, 0, stream>>>(dst, counts);
  k_scan<<<1, 1024, 0, stream>>>(counts, row_ptr, fillp);
  k_fill<<<(E_EDGES+255)/256, 256, 0, stream>>>(src, dst, fillp, pos_e, sorted_src);
  k_setup<<<1349, 256, 0, stream>>>(node_fts, xh, Ws, WsT, Wes, a_edge, b_edge);
  k_alpha_e<<<(E_EDGES+255)/256, 256, 0, stream>>>(edge_fts, pos_e, b_edge, ae_sorted);

  for(int hop=0; hop<HOPS; hop++){
    k_projm<<<dim3(157, 8), 256, 0, stream>>>(xh, WsT + (size_t)hop*512*128, h_all);
    k_s<<<2500, 256, 0, stream>>>(h_all, a_src + (size_t)hop*512, a_dst + (size_t)hop*512, s_src, s_dst);
    float* xout = (hop==0) ? xbuf : curbuf;
    k_softagg<<<N_NODES, 256, 0, stream>>>(ae_sorted + (size_t)hop*E_EDGES*4, s_src, s_dst,
                                           sorted_src, row_ptr, h_all, ew_fb, xout,
                                           (hop==0) ? xh : (_Float16*)nullptr);
    if(hop > 0){
      float* xnew = (hop == HOPS-1) ? (float*)d_out : xbuf;
      k_gate2<<<dim3(313, 2), 256, 0, stream>>>(xbuf, curbuf, W_prior, W_curr, xnew,
                                                (hop < HOPS-1) ? xh : (_Float16*)nullptr);
    }
  }
}